// Round 9
// baseline (334.467 us; speedup 1.0000x reference)
//
#include <hip/hip_runtime.h>
#include <hip/hip_bf16.h>
#include <stdint.h>

typedef __bf16 bf16_t;
typedef bf16_t bf16x8 __attribute__((ext_vector_type(8)));
typedef float f32x4 __attribute__((ext_vector_type(4)));

#define IN_F 4096
#define OUT_F 4096
#define M_ROWS 8192
#define RANK 16

// ---------------------------------------------------------------------------
// Kernel 1 (merged): blocks [0,8192) dequantize+LoRA-fold W -> bf16;
// blocks [8192, 24576) cast x f32 -> bf16. Independent jobs, one launch,
// so the cast's pure-BW phase overlaps the dequant's VALU phase.
// ---------------------------------------------------------------------------
__global__ __launch_bounds__(256)
void prep_kernel(const float* __restrict__ x, const int* __restrict__ qw,
                 const float* __restrict__ wmax, const float* __restrict__ lA,
                 const float* __restrict__ lB, bf16_t* __restrict__ Wp,
                 bf16_t* __restrict__ Xb) {
  const int b = blockIdx.x;
  if (b >= 8192) {
    // ---- cast part ----
    const size_t tid = (size_t)(b - 8192) * 256 + threadIdx.x;
    const float4 a0 = *(const float4*)(x + tid * 8);
    const float4 a1 = *(const float4*)(x + tid * 8 + 4);
    bf16x8 o;
    o[0] = (bf16_t)a0.x; o[1] = (bf16_t)a0.y; o[2] = (bf16_t)a0.z; o[3] = (bf16_t)a0.w;
    o[4] = (bf16_t)a1.x; o[5] = (bf16_t)a1.y; o[6] = (bf16_t)a1.z; o[7] = (bf16_t)a1.w;
    *(bf16x8*)(Xb + tid * 8) = o;
    return;
  }
  // ---- dequant + LoRA part (8 o-rows x 256 i-cols per block) ----
  const int bo = b >> 4;
  const int bi = b & 15;
  const int t  = threadIdx.x;
  const int o  = bo * 8 + (t >> 5);
  const int i0 = bi * 256 + (t & 31) * 8;
  const int f0 = o * IN_F + i0;

  const int4 q4 = *(const int4*)(qw + (f0 >> 1));
  const float scale = wmax[f0 >> 6];
  const float st = scale * (2.0f / 15.0f);

  float v[8];
  {
    const int q0 = q4.x, q1 = q4.y, q2 = q4.z, q3 = q4.w;
    v[0] = (float)(q0 & 15)        * st - scale;
    v[1] = (float)((q0 >> 4) & 15) * st - scale;
    v[2] = (float)(q1 & 15)        * st - scale;
    v[3] = (float)((q1 >> 4) & 15) * st - scale;
    v[4] = (float)(q2 & 15)        * st - scale;
    v[5] = (float)((q2 >> 4) & 15) * st - scale;
    v[6] = (float)(q3 & 15)        * st - scale;
    v[7] = (float)((q3 >> 4) & 15) * st - scale;
  }

  const float* Brow = lB + o * RANK;
#pragma unroll
  for (int r = 0; r < RANK; ++r) {
    const float br = Brow[r];
    const float4 a0 = *(const float4*)(lA + r * IN_F + i0);
    const float4 a1 = *(const float4*)(lA + r * IN_F + i0 + 4);
    v[0] += br * a0.x; v[1] += br * a0.y; v[2] += br * a0.z; v[3] += br * a0.w;
    v[4] += br * a1.x; v[5] += br * a1.y; v[6] += br * a1.z; v[7] += br * a1.w;
  }

  bf16x8 ov;
#pragma unroll
  for (int j = 0; j < 8; ++j) ov[j] = (bf16_t)v[j];
  *(bf16x8*)(Wp + (size_t)f0) = ov;
}

// ---------------------------------------------------------------------------
// Kernel 2: 128x256-tile GEMM, BK=32, 48 KiB LDS, regs<=128 -> 2 blocks/CU.
// The two co-resident blocks anti-phase: one block's ds_read burst overlaps
// the other's MFMA burst (the overlap no intra-block schedule achieved).
// 8 waves (2M x 4N), 64x64/wave, acc[4][4] (64 VGPR).
// Swizzle (64-B rows): phys slot = kg ^ ((row>>1)&3)  -> 2-way banks (free);
// staging source inverse-permuted (both-sides). Counted vmcnt(3).
// ---------------------------------------------------------------------------
__device__ __forceinline__ void gld(const bf16_t* src, char* dst) {
  __builtin_amdgcn_global_load_lds((const __attribute__((address_space(1))) void*)src,
                                   (__attribute__((address_space(3))) void*)dst, 16, 0, 0);
}

#define BARRIER() __builtin_amdgcn_s_barrier()
#define WAIT_LGKM0() do { asm volatile("s_waitcnt lgkmcnt(0)" ::: "memory"); \
                          __builtin_amdgcn_sched_barrier(0); } while (0)
#define WAIT_VM(n) asm volatile("s_waitcnt vmcnt(" #n ")" ::: "memory")

// one K-tile stage: A 8 KB (1 gload) + B 16 KB (2 gloads) = 3 vmem ops/wave
#define STAGE(kt, buf) do { \
  gld(Asrc + (size_t)(kt) * 32,                      ldsA + (buf)*8192  + tid*16); \
  gld(Bsrc + (size_t)(kt) * 32,                      ldsB + (buf)*16384 + tid*16); \
  gld(Bsrc + (size_t)128*IN_F + (size_t)(kt) * 32,   ldsB + (buf)*16384 + 8192 + tid*16); \
} while (0)

#define LDAf(buf, m) (*(const bf16x8*)(ldsA + (buf)*8192  + aRowB + (m)*1024 + cSw))
#define LDBf(buf, n) (*(const bf16x8*)(ldsB + (buf)*16384 + bRowB + (n)*1024 + cSw))

// One K-tile: read 8 frags -> own-reads-done -> barrier (all waves done with
// cur) -> issue async stage of t+2 INTO cur -> MFMA burst -> counted vm wait
// (drains t+1's batch; leaves t+2's in flight) -> barrier.
#define TILE(CUR, STG, TW) do { \
  _Pragma("unroll") for (int m = 0; m < 4; ++m) a[m] = LDAf(CUR, m); \
  _Pragma("unroll") for (int n = 0; n < 4; ++n) b[n] = LDBf(CUR, n); \
  WAIT_LGKM0(); \
  BARRIER(); \
  STG; \
  __builtin_amdgcn_s_setprio(1); \
  _Pragma("unroll") for (int m = 0; m < 4; ++m) \
  _Pragma("unroll") for (int n = 0; n < 4; ++n) \
    acc[m][n] = __builtin_amdgcn_mfma_f32_16x16x32_bf16(a[m], b[n], acc[m][n], 0, 0, 0); \
  __builtin_amdgcn_s_setprio(0); \
  TW; \
  BARRIER(); \
} while (0)

__global__ __launch_bounds__(512, 4)
void gemm_occ2_kernel(const bf16_t* __restrict__ Xb, const bf16_t* __restrict__ Wp,
                      const float* __restrict__ bias, float* __restrict__ C) {
  __shared__ __align__(16) bf16_t As[2 * 4096];    // 16 KiB: [2buf][128 rows][64 B]
  __shared__ __align__(16) bf16_t Bs[2 * 8192];    // 32 KiB: [2buf][256 rows][64 B]
  char* ldsA = (char*)As;
  char* ldsB = (char*)Bs;

  const int tid  = threadIdx.x;
  const int lane = tid & 63;
  const int wave = tid >> 6;
  const int wr = wave >> 2;            // 0..1 -> M half (64 rows)
  const int wc = wave & 3;             // 0..3 -> N quarter (64 cols)
  const int r16 = lane & 15;
  const int kg  = lane >> 4;           // 0..3

  // bijective XCD swizzle: 1024 wgs, 128/XCD chunk
  const int bid  = blockIdx.x;
  const int wgid = (bid & 7) * 128 + (bid >> 3);
  const int bm = wgid >> 4;            // 0..63
  const int bn = wgid & 15;            // 0..15

  // staging: linear dest tid*16 -> dest row=tid>>2, dest slot=tid&3;
  // source slot = (tid&3) ^ ((row>>1)&3) = (tid&3) ^ ((tid>>3)&3)
  const int srow = tid >> 2;                        // 0..127
  const int ss   = (tid & 3) ^ ((tid >> 3) & 3);    // source slot (8 elems)
  const bf16_t* Asrc = Xb + (size_t)(bm * 128 + srow) * IN_F + ss * 8;
  const bf16_t* Bsrc = Wp + (size_t)(bn * 256 + srow) * IN_F + ss * 8;

  // read side: row bytes = row*64; slot byte = (kg ^ ((r16>>1)&3))*16
  const int cSw   = (kg ^ ((r16 >> 1) & 3)) * 16;
  const int aRowB = (wr * 64 + r16) * 64;           // + m*1024
  const int bRowB = (wc * 64 + r16) * 64;           // + n*1024

  f32x4 acc[4][4] = {};
  bf16x8 a[4], b[4];

  // prologue: stage tiles 0,1
  STAGE(0, 0);
  STAGE(1, 1);
  WAIT_VM(3);                  // tile 0 landed; tile 1's 3 in flight
  BARRIER();

  for (int tt = 0; tt < 124; tt += 2) {
    TILE(0, STAGE(tt + 2, 0), WAIT_VM(3));
    TILE(1, STAGE(tt + 3, 1), WAIT_VM(3));
  }
  TILE(0, STAGE(126, 0), WAIT_VM(3));   // t=124
  TILE(1, STAGE(127, 1), WAIT_VM(3));   // t=125
  TILE(0, {},            WAIT_VM(0));   // t=126 (drain t=127's batch)
  TILE(1, {},            {});           // t=127

  // epilogue: C/D layout col=lane&15, row=kg*4+reg (m89-verified)
#pragma unroll
  for (int n = 0; n < 4; ++n) {
    const int col = bn * 256 + wc * 64 + n * 16 + r16;
    const float bv = bias[col];
#pragma unroll
    for (int m = 0; m < 4; ++m) {
      const int row0 = bm * 128 + wr * 64 + m * 16 + kg * 4;
#pragma unroll
      for (int r = 0; r < 4; ++r)
        C[(size_t)(row0 + r) * OUT_F + col] = acc[m][n][r] + bv;
    }
  }
}

// ---------------------------------------------------------------------------
extern "C" void kernel_launch(void* const* d_in, const int* in_sizes, int n_in,
                              void* d_out, int out_size, void* d_ws, size_t ws_size,
                              hipStream_t stream) {
  const float* x  = (const float*)d_in[0];
  const int*   qw = (const int*)d_in[1];
  const float* wm = (const float*)d_in[2];
  const float* lA = (const float*)d_in[3];
  const float* lB = (const float*)d_in[4];
  const float* bs = (const float*)d_in[5];
  float* out = (float*)d_out;

  bf16_t* Wp = (bf16_t*)d_ws;                                        // 33.5 MB
  bf16_t* Xb = (bf16_t*)((char*)d_ws + (size_t)OUT_F * IN_F * 2);    // 67 MB

  prep_kernel<<<24576, 256, 0, stream>>>(x, qw, wm, lA, lB, Wp, Xb);
  gemm_occ2_kernel<<<(M_ROWS / 128) * (OUT_F / 256), 512, 0, stream>>>(Xb, Wp, bs, out);
}